// Round 4
// baseline (214.742 us; speedup 1.0000x reference)
//
#include <hip/hip_runtime.h>
#include <hip/hip_bf16.h>
#include <stdint.h>

// RBF dense layer: out[b][u] = exp(-gamma * max(|x_b|^2 + |k_u|^2 - 2*x_b.k_u, 0)) + bias[u]
// B=8192, D=512, U=4096, fp32 in/out. gamma = 1.0.
// 256x256 8-wave GEMM, template-faithful phases (2 barriers/phase), T1 XCD swizzle,
// T2 full 3-bit XOR chunk swizzle, T3/T4 counted vmcnt (never 0 in-loop), T5 setprio.
// Prep merged into one kernel. Fallback direct fp32 path if ws too small.

using short8 = __attribute__((ext_vector_type(8))) short;
using bf16x8 = __attribute__((ext_vector_type(8))) __bf16;
using f32x4  = __attribute__((ext_vector_type(4))) float;
typedef unsigned short ushort_t;

#define GAMMA_F 1.0f

__device__ __forceinline__ ushort_t f2bf(float f) {
  unsigned u = __float_as_uint(f);
  u = (u + 0x7fffu + ((u >> 16) & 1u)) >> 16;  // RNE
  return (ushort_t)u;
}

// ---- merged prep ----
// blocks [0,2048): x rows -> xb bf16 [8192][512] + xsq
// blocks [2048,2112): kernel [512][4096] -> kbT bf16 [4096][512] + ksq (no atomics)
__global__ __launch_bounds__(256) void prep_kernel(
    const float* __restrict__ x, const float* __restrict__ kern,
    ushort_t* __restrict__ xb, ushort_t* __restrict__ kbT,
    float* __restrict__ xsq, float* __restrict__ ksq) {
  const int t = threadIdx.x;
  if (blockIdx.x < 2048) {
    const int w = t >> 6, l = t & 63;
    const int r = blockIdx.x * 4 + w;
    const float4* xr = (const float4*)(x + (size_t)r * 512);
    float4 v0 = xr[l * 2 + 0];
    float4 v1 = xr[l * 2 + 1];
    float s = v0.x * v0.x + v0.y * v0.y + v0.z * v0.z + v0.w * v0.w
            + v1.x * v1.x + v1.y * v1.y + v1.z * v1.z + v1.w * v1.w;
    short8 p;
    p[0] = (short)f2bf(v0.x); p[1] = (short)f2bf(v0.y);
    p[2] = (short)f2bf(v0.z); p[3] = (short)f2bf(v0.w);
    p[4] = (short)f2bf(v1.x); p[5] = (short)f2bf(v1.y);
    p[6] = (short)f2bf(v1.z); p[7] = (short)f2bf(v1.w);
    *(short8*)(xb + (size_t)r * 512 + l * 8) = p;
#pragma unroll
    for (int o = 32; o > 0; o >>= 1) s += __shfl_xor(s, o);
    if (l == 0) xsq[r] = s;
  } else {
    __shared__ ushort_t tile[64][65];
    __shared__ float red[4][64];
    const int u0 = (blockIdx.x - 2048) * 64;
    const int c = t & 63, tq = t >> 6;
    float part = 0.f;
    for (int d0 = 0; d0 < 512; d0 += 64) {
#pragma unroll
      for (int i = 0; i < 16; ++i) {
        const int r = tq * 16 + i;
        const float v = kern[(size_t)(d0 + r) * 4096 + u0 + c];
        part += v * v;
        tile[r][c] = f2bf(v);
      }
      __syncthreads();
      const int dl = (t & 7) * 8;
#pragma unroll
      for (int h = 0; h < 2; ++h) {
        const int ul = (t >> 3) + h * 32;
        short8 v;
#pragma unroll
        for (int j = 0; j < 8; ++j) ((ushort_t*)&v)[j] = tile[dl + j][ul];
        *(short8*)(kbT + (size_t)(u0 + ul) * 512 + d0 + dl) = v;
      }
      __syncthreads();
    }
    red[tq][c] = part;
    __syncthreads();
    if (t < 64) ksq[u0 + t] = red[0][t] + red[1][t] + red[2][t] + red[3][t];
  }
}

// ---- 256x256 GEMM + fused RBF epilogue ----
// 512 thr (8 waves: wr=w>>2, wc=w&3), per-wave 128x64 output.
// LDS: A,B each [2 dbuf][256 rows][64 k] bf16 = 64 KiB -> 128 KiB, 1 block/CU.
// K-step s computes from dbuf s&1 while tile s+1 streams into dbuf (s+1)&1
// (its readers finished at the end of step s-1; barrier-separated).
// Per phase (quadrant): ds_read -> s_barrier -> (lgkm by compiler) setprio+MFMA
// -> s_barrier  [2 barriers/phase, template-faithful].
// Swizzle: physical 16B chunk = logical ^ (row&7); pre-swizzled global source,
// linear global_load_lds dest, XOR applied again on ds_read (involution).
__global__ __launch_bounds__(512, 2) void rbf_gemm8_kernel(
    const ushort_t* __restrict__ xb, const ushort_t* __restrict__ kbT,
    const float* __restrict__ xsq, const float* __restrict__ ksq,
    const float* __restrict__ bias, float* __restrict__ out) {
  __shared__ ushort_t A_lds[2 * 256 * 64];  // 64 KiB
  __shared__ ushort_t B_lds[2 * 256 * 64];  // 64 KiB

  const int tid = threadIdx.x;
  const int w = tid >> 6, l = tid & 63;
  const int wr = w >> 2, wc = w & 3;

  // T1: bijective XCD swizzle (nwg=512, 512%8==0)
  const int tile = ((blockIdx.x & 7) << 6) + (blockIdx.x >> 3);
  const int brow = (tile >> 4) * 256;   // 32 row-tiles
  const int bcol = (tile & 15) * 256;   // 16 col-tiles

  // staging: thread t -> row t>>3 (+i*64), chunk t&7; source chunk pre-swizzled
  const int srow = tid >> 3;
  const int sj = (tid & 7) ^ ((tid >> 3) & 7);
  const ushort_t* gA0 = xb  + (size_t)(brow + srow) * 512 + sj * 8;
  const ushort_t* gB0 = kbT + (size_t)(bcol + srow) * 512 + sj * 8;
  const int ldsw = w * 512;  // wave-uniform LDS base (elements)

#define STAGE_TILE(kt, dn) do {                                                   \
    const ushort_t* _ga = gA0 + (size_t)(kt) * 64;                                \
    const ushort_t* _gb = gB0 + (size_t)(kt) * 64;                                \
    const int _lb = (dn) * 16384 + ldsw;                                          \
    _Pragma("unroll")                                                             \
    for (int i = 0; i < 4; ++i)                                                   \
      __builtin_amdgcn_global_load_lds(                                           \
          (const __attribute__((address_space(1))) void*)(_ga + (size_t)i * 32768),\
          (__attribute__((address_space(3))) void*)(&A_lds[_lb + i * 4096]), 16, 0, 0); \
    _Pragma("unroll")                                                             \
    for (int i = 0; i < 4; ++i)                                                   \
      __builtin_amdgcn_global_load_lds(                                           \
          (const __attribute__((address_space(1))) void*)(_gb + (size_t)i * 32768),\
          (__attribute__((address_space(3))) void*)(&B_lds[_lb + i * 4096]), 16, 0, 0); \
  } while (0)

  // per-thread ds_read swizzled chunk offsets (elements)
  const int l15 = l & 15, l4 = l >> 4, l7 = l & 7;
  const int chk0 = (l4 ^ l7) * 8;        // k in [0,32)
  const int chk1 = ((4 + l4) ^ l7) * 8;  // k in [32,64)
  const int aoff = (wr * 128 + l15) * 64;
  const int boff = (wc * 64 + l15) * 64;

  f32x4 acc[8][4] = {};

  // phase = one C-quadrant x BK=64: 12 ds_read_b128, 2 barriers, 16 MFMA
#define MFMA_PHASE(mh, nh, dbase) do {                                            \
    bf16x8 _a[4][2], _b[2][2];                                                    \
    _Pragma("unroll")                                                             \
    for (int i = 0; i < 4; ++i) {                                                 \
      _a[i][0] = *(const bf16x8*)&A_lds[(dbase) + aoff + ((mh)*4 + i) * 1024 + chk0]; \
      _a[i][1] = *(const bf16x8*)&A_lds[(dbase) + aoff + ((mh)*4 + i) * 1024 + chk1]; \
    }                                                                             \
    _Pragma("unroll")                                                             \
    for (int j = 0; j < 2; ++j) {                                                 \
      _b[j][0] = *(const bf16x8*)&B_lds[(dbase) + boff + ((nh)*2 + j) * 1024 + chk0]; \
      _b[j][1] = *(const bf16x8*)&B_lds[(dbase) + boff + ((nh)*2 + j) * 1024 + chk1]; \
    }                                                                             \
    asm volatile("s_barrier" ::: "memory");                                       \
    __builtin_amdgcn_s_setprio(1);                                                \
    _Pragma("unroll")                                                             \
    for (int i = 0; i < 4; ++i)                                                   \
      _Pragma("unroll")                                                           \
      for (int j = 0; j < 2; ++j) {                                               \
        acc[(mh)*4 + i][(nh)*2 + j] = __builtin_amdgcn_mfma_f32_16x16x32_bf16(    \
            _a[i][0], _b[j][0], acc[(mh)*4 + i][(nh)*2 + j], 0, 0, 0);            \
        acc[(mh)*4 + i][(nh)*2 + j] = __builtin_amdgcn_mfma_f32_16x16x32_bf16(    \
            _a[i][1], _b[j][1], acc[(mh)*4 + i][(nh)*2 + j], 0, 0, 0);            \
      }                                                                           \
    __builtin_amdgcn_s_setprio(0);                                                \
    __builtin_amdgcn_sched_barrier(0);                                            \
    asm volatile("s_barrier" ::: "memory");                                       \
  } while (0)

  // prologue: stage K-tile 0 -> dbuf 0 (8 issues in flight)
  STAGE_TILE(0, 0);

#pragma unroll 2
  for (int s = 0; s < 8; ++s) {
    const int dbase = (s & 1) * 16384;
    // burst-issue next tile (max slack), counted wait for current tile's 8
    STAGE_TILE((s + 1) & 7, (s + 1) & 1);
    asm volatile("s_waitcnt vmcnt(8)" ::: "memory");
    asm volatile("s_barrier" ::: "memory");
    MFMA_PHASE(0, 0, dbase);
    MFMA_PHASE(0, 1, dbase);
    MFMA_PHASE(1, 0, dbase);
    MFMA_PHASE(1, 1, dbase);
  }

  // epilogue: C/D frag layout col=lane&15, row=(lane>>4)*4+reg (m89/m91)
  const int cl = l15, rg = l4 * 4;
#pragma unroll
  for (int n = 0; n < 4; ++n) {
    const int gc = bcol + wc * 64 + n * 16 + cl;
    const float kq = ksq[gc];
    const float bz = bias[gc];
#pragma unroll
    for (int m = 0; m < 8; ++m) {
      const int gr0 = brow + wr * 128 + m * 16 + rg;
      const float4 xq = *(const float4*)&xsq[gr0];
      const float xq4[4] = {xq.x, xq.y, xq.z, xq.w};
#pragma unroll
      for (int j = 0; j < 4; ++j) {
        float d2 = xq4[j] + kq - 2.0f * acc[m][n][j];
        d2 = fmaxf(d2, 0.0f);
        out[(size_t)(gr0 + j) * 4096 + gc] = __expf(-GAMMA_F * d2) + bz;
      }
    }
  }
#undef STAGE_TILE
#undef MFMA_PHASE
}

// ---- fallback (ws too small): direct fp32 ----
__global__ __launch_bounds__(256) void rbf_direct_kernel(
    const float* __restrict__ x, const float* __restrict__ kern,
    const float* __restrict__ bias, float* __restrict__ out) {
  __shared__ float Xs[64][17];
  __shared__ float Ks[16][65];
  const int tid = threadIdx.x;
  const int brow = blockIdx.y * 64, bcol = blockIdx.x * 64;
  const int tr = (tid >> 4) * 4, tc = (tid & 15) * 4;
  float acc[4][4] = {};
  for (int k0 = 0; k0 < 512; k0 += 16) {
    {
      const int r = tid >> 2, c = (tid & 3) * 4;
      float4 v = *(const float4*)&x[(size_t)(brow + r) * 512 + k0 + c];
      Xs[r][c] = v.x; Xs[r][c + 1] = v.y; Xs[r][c + 2] = v.z; Xs[r][c + 3] = v.w;
    }
    {
      const int r = tid >> 4, c = (tid & 15) * 4;
      float4 v = *(const float4*)&kern[(size_t)(k0 + r) * 4096 + bcol + c];
      Ks[r][c] = v.x; Ks[r][c + 1] = v.y; Ks[r][c + 2] = v.z; Ks[r][c + 3] = v.w;
    }
    __syncthreads();
#pragma unroll
    for (int kk = 0; kk < 16; ++kk) {
      float a[4], b[4];
#pragma unroll
      for (int i = 0; i < 4; ++i) a[i] = Xs[tr + i][kk];
#pragma unroll
      for (int j = 0; j < 4; ++j) b[j] = Ks[kk][tc + j];
#pragma unroll
      for (int i = 0; i < 4; ++i)
#pragma unroll
        for (int j = 0; j < 4; ++j) {
          float d = a[i] - b[j];
          acc[i][j] = fmaf(d, d, acc[i][j]);
        }
    }
    __syncthreads();
  }
#pragma unroll
  for (int i = 0; i < 4; ++i)
#pragma unroll
    for (int j = 0; j < 4; ++j)
      out[(size_t)(brow + tr + i) * 4096 + bcol + tc + j] =
          __expf(-GAMMA_F * acc[i][j]) + bias[bcol + tc + j];
}

extern "C" void kernel_launch(void* const* d_in, const int* in_sizes, int n_in,
                              void* d_out, int out_size, void* d_ws, size_t ws_size,
                              hipStream_t stream) {
  const float* x    = (const float*)d_in[0];   // 8192*512
  const float* kern = (const float*)d_in[1];   // 512*4096
  const float* bias = (const float*)d_in[2];   // 4096
  float* out = (float*)d_out;                  // 8192*4096 f32

  const size_t NEED = 8388608 /*xb*/ + 4194304 /*kbT*/ + 32768 /*xsq*/ + 16384 /*ksq*/;
  if (ws_size < NEED) {
    rbf_direct_kernel<<<dim3(64, 128), 256, 0, stream>>>(x, kern, bias, out);
    return;
  }

  char* ws = (char*)d_ws;
  ushort_t* xb  = (ushort_t*)(ws);                 // 8 MiB bf16 x
  ushort_t* kbT = (ushort_t*)(ws + 8388608);       // 4 MiB bf16 kernel^T
  float* xsq = (float*)(ws + 8388608 + 4194304);   // 32 KiB row norms
  float* ksq = xsq + 8192;                         // 16 KiB col norms

  prep_kernel<<<2112, 256, 0, stream>>>(x, kern, xb, kbT, xsq, ksq);
  rbf_gemm8_kernel<<<512, 512, 0, stream>>>(xb, kbT, xsq, ksq, bias, out);
}

// Round 8
// 200.228 us; speedup vs baseline: 1.0725x; 1.0725x over previous
//
#include <hip/hip_runtime.h>
#include <hip/hip_bf16.h>
#include <stdint.h>

// RBF dense layer: out[b][u] = exp(-gamma * max(|x_b|^2 + |k_u|^2 - 2*x_b.k_u, 0)) + bias[u]
// B=8192, D=512, U=4096, fp32 in/out. gamma = 1.0.
// 128x128 tile / 4 waves (best FLOP per LDS byte), explicit LDS double-buffer
// (64 KiB -> 2 blocks/CU for write/compute overlap), minimal fragment reads
// (16 ds_read_b128 per wave per K-step), 2 barriers per K-step, counted
// vmcnt(8), T1 XCD swizzle, T2 involution chunk swizzle, T5 setprio.

using short8 = __attribute__((ext_vector_type(8))) short;
using bf16x8 = __attribute__((ext_vector_type(8))) __bf16;
using f32x4  = __attribute__((ext_vector_type(4))) float;
typedef unsigned short ushort_t;

#define GAMMA_F 1.0f

__device__ __forceinline__ ushort_t f2bf(float f) {
  unsigned u = __float_as_uint(f);
  u = (u + 0x7fffu + ((u >> 16) & 1u)) >> 16;  // RNE
  return (ushort_t)u;
}

// ---- merged prep ----
// blocks [0,2048): x rows -> xb bf16 [8192][512] + xsq
// blocks [2048,2112): kernel [512][4096] -> kbT bf16 [4096][512] + ksq
__global__ __launch_bounds__(256) void prep_kernel(
    const float* __restrict__ x, const float* __restrict__ kern,
    ushort_t* __restrict__ xb, ushort_t* __restrict__ kbT,
    float* __restrict__ xsq, float* __restrict__ ksq) {
  const int t = threadIdx.x;
  if (blockIdx.x < 2048) {
    const int w = t >> 6, l = t & 63;
    const int r = blockIdx.x * 4 + w;
    const float4* xr = (const float4*)(x + (size_t)r * 512);
    float4 v0 = xr[l * 2 + 0];
    float4 v1 = xr[l * 2 + 1];
    float s = v0.x * v0.x + v0.y * v0.y + v0.z * v0.z + v0.w * v0.w
            + v1.x * v1.x + v1.y * v1.y + v1.z * v1.z + v1.w * v1.w;
    short8 p;
    p[0] = (short)f2bf(v0.x); p[1] = (short)f2bf(v0.y);
    p[2] = (short)f2bf(v0.z); p[3] = (short)f2bf(v0.w);
    p[4] = (short)f2bf(v1.x); p[5] = (short)f2bf(v1.y);
    p[6] = (short)f2bf(v1.z); p[7] = (short)f2bf(v1.w);
    *(short8*)(xb + (size_t)r * 512 + l * 8) = p;
#pragma unroll
    for (int o = 32; o > 0; o >>= 1) s += __shfl_xor(s, o);
    if (l == 0) xsq[r] = s;
  } else {
    __shared__ ushort_t tile[64][65];
    __shared__ float red[4][64];
    const int u0 = (blockIdx.x - 2048) * 64;
    const int c = t & 63, tq = t >> 6;
    float part = 0.f;
    for (int d0 = 0; d0 < 512; d0 += 64) {
#pragma unroll
      for (int i = 0; i < 16; ++i) {
        const int r = tq * 16 + i;
        const float v = kern[(size_t)(d0 + r) * 4096 + u0 + c];
        part += v * v;
        tile[r][c] = f2bf(v);
      }
      __syncthreads();
      const int dl = (t & 7) * 8;
#pragma unroll
      for (int h = 0; h < 2; ++h) {
        const int ul = (t >> 3) + h * 32;
        short8 v;
#pragma unroll
        for (int j = 0; j < 8; ++j) ((ushort_t*)&v)[j] = tile[dl + j][ul];
        *(short8*)(kbT + (size_t)(u0 + ul) * 512 + d0 + dl) = v;
      }
      __syncthreads();
    }
    red[tq][c] = part;
    __syncthreads();
    if (t < 64) ksq[u0 + t] = red[0][t] + red[1][t] + red[2][t] + red[3][t];
  }
}

// ---- 128x128 double-buffered GEMM + fused RBF epilogue ----
// 256 thr = 4 waves (wr=w>>1, wc=w&1), wave-tile 64x64 (4m x 4n of 16x16x32).
// LDS: A,B each [2 dbuf][128 rows][64 k] bf16 = 32 KiB -> 64 KiB total,
// 2 blocks/CU co-resident (epilogue/staging of one overlaps MFMA of the other).
// Per K-step: STAGE next tile (8 gload_lds) -> vmcnt(8) -> barrier ->
// 16 ds_read_b128 (each fragment read ONCE) -> 32 MFMA (setprio) -> barrier.
// NOTE: vmcnt(8)+barrier pairing is what makes OTHER waves' staging visible —
// every wave drains its own 8, then the barrier joins them. Do not reorder.
__global__ __launch_bounds__(256, 2) void rbf_gemm_kernel(
    const ushort_t* __restrict__ xb, const ushort_t* __restrict__ kbT,
    const float* __restrict__ xsq, const float* __restrict__ ksq,
    const float* __restrict__ bias, float* __restrict__ out) {
  __shared__ ushort_t A_lds[2 * 128 * 64];  // 32 KiB
  __shared__ ushort_t B_lds[2 * 128 * 64];  // 32 KiB

  const int tid = threadIdx.x;
  const int w = tid >> 6, l = tid & 63;
  const int wr = w >> 1, wc = w & 1;

  // T1: bijective XCD swizzle (nwg=2048, 2048%8==0, q=256)
  const int wgid = ((blockIdx.x & 7) << 8) + (blockIdx.x >> 3);
  const int brow = (wgid >> 5) * 128;  // 64 row-tiles; consecutive ids share brow
  const int bcol = (wgid & 31) * 128;  // 32 col-tiles

  // staging: thread t -> row t>>3 (+i*32), chunk t&7; source chunk pre-swizzled
  const int srow = tid >> 3;
  const int sj = (tid & 7) ^ ((tid >> 3) & 7);
  const ushort_t* gA0 = xb  + (size_t)(brow + srow) * 512 + sj * 8;
  const ushort_t* gB0 = kbT + (size_t)(bcol + srow) * 512 + sj * 8;
  // per issue i: wave w covers rows i*32 + w*8 .. +7 -> LDS elems i*2048 + w*512
  const int ldsw = w * 512;

#define STAGE_TILE(kt, dn) do {                                                   \
    const ushort_t* _ga = gA0 + (size_t)(kt) * 64;                                \
    const ushort_t* _gb = gB0 + (size_t)(kt) * 64;                                \
    const int _lb = (dn) * 8192 + ldsw;                                           \
    _Pragma("unroll")                                                             \
    for (int i = 0; i < 4; ++i)                                                   \
      __builtin_amdgcn_global_load_lds(                                           \
          (const __attribute__((address_space(1))) void*)(_ga + (size_t)i * 16384),\
          (__attribute__((address_space(3))) void*)(&A_lds[_lb + i * 2048]), 16, 0, 0); \
    _Pragma("unroll")                                                             \
    for (int i = 0; i < 4; ++i)                                                   \
      __builtin_amdgcn_global_load_lds(                                           \
          (const __attribute__((address_space(1))) void*)(_gb + (size_t)i * 16384),\
          (__attribute__((address_space(3))) void*)(&B_lds[_lb + i * 2048]), 16, 0, 0); \
  } while (0)

  // ds_read addressing: row = (wr|wc)*64 + f*16 + l15; row&7 == l15&7 == l7.
  // logical chunk (k/8) = ks*4 + l4; physical = (logical ^ l7) * 8 elems.
  const int l15 = l & 15, l4 = l >> 4, l7 = l & 7;
  const int chk0 = (l4 ^ l7) * 8;        // k in [0,32)
  const int chk1 = ((4 + l4) ^ l7) * 8;  // k in [32,64)
  const int aoff = (wr * 64 + l15) * 64;
  const int boff = (wc * 64 + l15) * 64;

  f32x4 acc[4][4] = {};

  // prologue: stage K-tile 0 -> dbuf 0
  STAGE_TILE(0, 0);

#pragma unroll 2
  for (int s = 0; s < 8; ++s) {
    const int dbase = (s & 1) * 8192;
    // issue next tile into the other buffer (its readers finished at step s-1's
    // trailing barrier), then counted wait for the current tile's 8 loads.
    // s=7 re-stages tile 0 (wasted but keeps vmcnt counts uniform; L2-hit).
    STAGE_TILE((s + 1) & 7, (s + 1) & 1);
    asm volatile("s_waitcnt vmcnt(8)" ::: "memory");
    asm volatile("s_barrier" ::: "memory");

    // minimal fragment reads: each of 8 a-frags / 8 b-frags read exactly once
    bf16x8 a0[4], a1[4], b0[4], b1[4];
#pragma unroll
    for (int m = 0; m < 4; ++m) {
      a0[m] = *(const bf16x8*)&A_lds[dbase + aoff + m * 1024 + chk0];
      a1[m] = *(const bf16x8*)&A_lds[dbase + aoff + m * 1024 + chk1];
    }
#pragma unroll
    for (int n = 0; n < 4; ++n) {
      b0[n] = *(const bf16x8*)&B_lds[dbase + boff + n * 1024 + chk0];
      b1[n] = *(const bf16x8*)&B_lds[dbase + boff + n * 1024 + chk1];
    }
    __builtin_amdgcn_s_setprio(1);
#pragma unroll
    for (int m = 0; m < 4; ++m)
#pragma unroll
      for (int n = 0; n < 4; ++n)
        acc[m][n] = __builtin_amdgcn_mfma_f32_16x16x32_bf16(a0[m], b0[n], acc[m][n], 0, 0, 0);
#pragma unroll
    for (int m = 0; m < 4; ++m)
#pragma unroll
      for (int n = 0; n < 4; ++n)
        acc[m][n] = __builtin_amdgcn_mfma_f32_16x16x32_bf16(a1[m], b1[n], acc[m][n], 0, 0, 0);
    __builtin_amdgcn_s_setprio(0);
    __builtin_amdgcn_sched_barrier(0);
    // trailing barrier: after all waves pass, next step may overwrite this buffer
    asm volatile("s_barrier" ::: "memory");
  }

  // epilogue: C/D frag layout col=lane&15, row=(lane>>4)*4+reg (m89/m91)
  const int cl = l15, rg = l4 * 4;
#pragma unroll
  for (int n = 0; n < 4; ++n) {
    const int gc = bcol + wc * 64 + n * 16 + cl;
    const float kq = ksq[gc];
    const float bz = bias[gc];
#pragma unroll
    for (int m = 0; m < 4; ++m) {
      const int gr0 = brow + wr * 64 + m * 16 + rg;
      const float4 xq = *(const float4*)&xsq[gr0];
      const float xq4[4] = {xq.x, xq.y, xq.z, xq.w};
#pragma unroll
      for (int j = 0; j < 4; ++j) {
        float d2 = xq4[j] + kq - 2.0f * acc[m][n][j];
        d2 = fmaxf(d2, 0.0f);
        out[(size_t)(gr0 + j) * 4096 + gc] = __expf(-GAMMA_F * d2) + bz;
      }
    }
  }
#undef STAGE_TILE
}

// ---- fallback (ws too small): direct fp32 ----
__global__ __launch_bounds__(256) void rbf_direct_kernel(
    const float* __restrict__ x, const float* __restrict__ kern,
    const float* __restrict__ bias, float* __restrict__ out) {
  __shared__ float Xs[64][17];
  __shared__ float Ks[16][65];
  const int tid = threadIdx.x;
  const int brow = blockIdx.y * 64, bcol = blockIdx.x * 64;
  const int tr = (tid >> 4) * 4, tc = (tid & 15) * 4;
  float acc[4][4] = {};
  for (int k0 = 0; k0 < 512; k0 += 16) {
    {
      const int r = tid >> 2, c = (tid & 3) * 4;
      float4 v = *(const float4*)&x[(size_t)(brow + r) * 512 + k0 + c];
      Xs[r][c] = v.x; Xs[r][c + 1] = v.y; Xs[r][c + 2] = v.z; Xs[r][c + 3] = v.w;
    }
    {
      const int r = tid >> 4, c = (tid & 15) * 4;
      float4 v = *(const float4*)&kern[(size_t)(k0 + r) * 4096 + bcol + c];
      Ks[r][c] = v.x; Ks[r][c + 1] = v.y; Ks[r][c + 2] = v.z; Ks[r][c + 3] = v.w;
    }
    __syncthreads();
#pragma unroll
    for (int kk = 0; kk < 16; ++kk) {
      float a[4], b[4];
#pragma unroll
      for (int i = 0; i < 4; ++i) a[i] = Xs[tr + i][kk];
#pragma unroll
      for (int j = 0; j < 4; ++j) b[j] = Ks[kk][tc + j];
#pragma unroll
      for (int i = 0; i < 4; ++i)
#pragma unroll
        for (int j = 0; j < 4; ++j) {
          float d = a[i] - b[j];
          acc[i][j] = fmaf(d, d, acc[i][j]);
        }
    }
    __syncthreads();
  }
#pragma unroll
  for (int i = 0; i < 4; ++i)
#pragma unroll
    for (int j = 0; j < 4; ++j)
      out[(size_t)(brow + tr + i) * 4096 + bcol + tc + j] =
          __expf(-GAMMA_F * acc[i][j]) + bias[bcol + tc + j];
}

extern "C" void kernel_launch(void* const* d_in, const int* in_sizes, int n_in,
                              void* d_out, int out_size, void* d_ws, size_t ws_size,
                              hipStream_t stream) {
  const float* x    = (const float*)d_in[0];   // 8192*512
  const float* kern = (const float*)d_in[1];   // 512*4096
  const float* bias = (const float*)d_in[2];   // 4096
  float* out = (float*)d_out;                  // 8192*4096 f32

  const size_t NEED = 8388608 /*xb*/ + 4194304 /*kbT*/ + 32768 /*xsq*/ + 16384 /*ksq*/;
  if (ws_size < NEED) {
    rbf_direct_kernel<<<dim3(64, 128), 256, 0, stream>>>(x, kern, bias, out);
    return;
  }

  char* ws = (char*)d_ws;
  ushort_t* xb  = (ushort_t*)(ws);                 // 8 MiB bf16 x
  ushort_t* kbT = (ushort_t*)(ws + 8388608);       // 4 MiB bf16 kernel^T
  float* xsq = (float*)(ws + 8388608 + 4194304);   // 32 KiB row norms
  float* ksq = xsq + 8192;                         // 16 KiB col norms

  prep_kernel<<<2112, 256, 0, stream>>>(x, kern, xb, kbT, xsq, ksq);
  rbf_gemm_kernel<<<2048, 256, 0, stream>>>(xb, kbT, xsq, ksq, bias, out);
}